// Round 6
// baseline (163.742 us; speedup 1.0000x reference)
//
#include <hip/hip_runtime.h>

// ---------------------------------------------------------------------------
// DeltaModel: B=256, L=2048, H=V=64.
//  (1) hs/k/v/q depend only on token id (V=64) -> 64-entry tables.
//  (2) r = M_N q -> backward scan: s_j = y^{(j-1)}[c_j], y += s_j*(-G[:,c_j]),
//      r += s_j v[c_j].  (GV stores {-G, v} so updates are positive fmas.)
//  (3) TWO INDEPENDENT BATCHES PER WAVE, interleaved at step granularity.
//      One wave/CU leaves every chain-hazard cycle dead (R1/R3/R4/R5 all
//      proved restructuring the chain trades stall for issue at a loss).
//      Instead, keep the baseline per-batch recipe UNCHANGED (bit-identical
//      math) and fill batch A's readlane->fma hazard slots with batch B's
//      ops. Issue/iter ~28cy >= chain cover -> ~24-28cy per 2 steps.
//      Columns prefetched via ring-8 (static indices, 0 bank conflicts).
// ---------------------------------------------------------------------------

#define DPP_ADD_F32(x, ctrl, rm, bm, bc)                                      \
  (x) = (x) + __int_as_float(__builtin_amdgcn_update_dpp(                     \
            0, __float_as_int(x), (ctrl), (rm), (bm), (bc)))

__device__ __forceinline__ float wave_sum64(float x) {
  DPP_ADD_F32(x, 0x111, 0xf, 0xf, true);   // row_shr:1
  DPP_ADD_F32(x, 0x112, 0xf, 0xf, true);   // row_shr:2
  DPP_ADD_F32(x, 0x114, 0xf, 0xf, true);   // row_shr:4
  DPP_ADD_F32(x, 0x118, 0xf, 0xf, true);   // row_shr:8
  DPP_ADD_F32(x, 0x142, 0xa, 0xf, false);  // row_bcast:15
  DPP_ADD_F32(x, 0x143, 0xc, 0xf, false);  // row_bcast:31 -> lane 63 total
  return __int_as_float(__builtin_amdgcn_readlane(__float_as_int(x), 63));
}

__device__ __forceinline__ float readlane_f(float x, int lane) {
  return __int_as_float(__builtin_amdgcn_readlane(__float_as_int(x), lane));
}

// ---------------------------------------------------------------------------
// Kernel A: per-token tables k_n, v, q (weights staged in padded LDS).
// ---------------------------------------------------------------------------
__global__ __launch_bounds__(64) void build_tables(
    const float* __restrict__ embed, const float* __restrict__ W1,
    const float* __restrict__ b1, const float* __restrict__ W2,
    const float* __restrict__ b2, const float* __restrict__ gamma,
    const float* __restrict__ beta, const float* __restrict__ Wk,
    const float* __restrict__ Wv, const float* __restrict__ Wq,
    float* __restrict__ k_tab, float* __restrict__ v_tab,
    float* __restrict__ q_tab) {
  __shared__ float Wbuf[8448];
  __shared__ float e_s[64];
  __shared__ float f1_s[128];
  __shared__ float hs_s[64];
  const int tok = blockIdx.x;
  const int l = threadIdx.x;

  const float e = embed[tok * 64 + l];
  e_s[l] = e;
  for (int i = 0; i < 128; ++i) Wbuf[i * 65 + l] = W1[i * 64 + l];
  __syncthreads();

  float a0 = b1[l], a1 = b1[l + 64];
#pragma unroll
  for (int h = 0; h < 64; ++h) {
    a0 = fmaf(e_s[h], Wbuf[l * 65 + h], a0);
    a1 = fmaf(e_s[h], Wbuf[(l + 64) * 65 + h], a1);
  }
  f1_s[l] = fmaxf(a0, 0.f);
  f1_s[l + 64] = fmaxf(a1, 0.f);
  __syncthreads();

  for (int i = 0; i < 128; ++i)
    Wbuf[(i >> 1) * 131 + (i & 1) * 64 + l] = W2[i * 64 + l];
  __syncthreads();

  float acc = b2[l];
#pragma unroll
  for (int j = 0; j < 128; ++j) acc = fmaf(f1_s[j], Wbuf[l * 131 + j], acc);
  const float hval = e + acc;

  const float mu = wave_sum64(hval) * (1.f / 64.f);
  const float d = hval - mu;
  const float var = wave_sum64(d * d) * (1.f / 64.f);
  const float hs = d * (1.f / sqrtf(var + 1e-5f)) * gamma[l] + beta[l];
  hs_s[l] = hs;
  __syncthreads();

  for (int i = 0; i < 64; ++i) {
    Wbuf[i * 65 + l] = Wk[i * 64 + l];
    Wbuf[4224 + i * 65 + l] = Wv[i * 64 + l];
  }
  __syncthreads();
  float kk = 0.f, vv = 0.f;
#pragma unroll
  for (int h = 0; h < 64; ++h) {
    kk = fmaf(hs_s[h], Wbuf[l * 65 + h], kk);
    vv = fmaf(hs_s[h], Wbuf[4224 + l * 65 + h], vv);
  }
  __syncthreads();
  for (int i = 0; i < 64; ++i) Wbuf[i * 65 + l] = Wq[i * 64 + l];
  __syncthreads();
  float qq = 0.f;
#pragma unroll
  for (int h = 0; h < 64; ++h) qq = fmaf(hs_s[h], Wbuf[l * 65 + h], qq);

  float nrm = fmaxf(sqrtf(wave_sum64(kk * kk)), 1e-12f);
  k_tab[tok * 64 + l] = kk / nrm;
  v_tab[tok * 64 + l] = vv;
  q_tab[tok * 64 + l] = qq;
}

// ---------------------------------------------------------------------------
// Kernel B: GV[a][l] = {-G[a][l], v[a][l]} packed float2 (G NEGATED so every
// downstream update is a positive fma); KQ[a][l] = q_a.k_l.
// ---------------------------------------------------------------------------
__global__ __launch_bounds__(64) void build_gram(
    const float* __restrict__ k_tab, const float* __restrict__ q_tab,
    const float* __restrict__ v_tab, float2* __restrict__ GV,
    float* __restrict__ KQ) {
  __shared__ float k_s[4160];
  __shared__ float q_s[64];
  const int a = blockIdx.x;
  const int l = threadIdx.x;
  for (int i = 0; i < 64; ++i) k_s[i * 65 + l] = k_tab[i * 64 + l];
  q_s[l] = q_tab[a * 64 + l];
  __syncthreads();
  float g = 0.f, kq = 0.f;
#pragma unroll
  for (int h = 0; h < 64; ++h) {
    g = fmaf(k_s[a * 65 + h], k_s[l * 65 + h], g);
    kq = fmaf(q_s[h], k_s[l * 65 + h], kq);
  }
  GV[a * 64 + l] = make_float2(-g, v_tab[a * 64 + l]);
  KQ[a * 64 + l] = kq;
}

// ---------------------------------------------------------------------------
// Kernel C: scan + head, TWO batches per wave (grid = 128), interleaved.
// Per-batch op sequence is identical to the verified baseline recipe.
// ---------------------------------------------------------------------------
__global__ __launch_bounds__(64, 1) void scan_head2(
    const int* __restrict__ seq, const float2* __restrict__ GVg,
    const float* __restrict__ KQ, const float* __restrict__ Wrp,
    const float* __restrict__ brp, const float* __restrict__ Wout,
    const float* __restrict__ bout, float* __restrict__ out) {
  __shared__ float2 GV_s[4160];  // 65 rows of 64 (row 64 = zeros, dummy tok)
  __shared__ float tmp[128];
  const int b0 = blockIdx.x * 2, b1 = b0 + 1;
  const int l = threadIdx.x;

#pragma unroll
  for (int i = 0; i < 32; ++i)
    ((float4*)GV_s)[l + 64 * i] = ((const float4*)GVg)[l + 64 * i];
  GV_s[4096 + l] = make_float2(0.f, 0.f);
  __syncthreads();

  const int* tp0 = seq + b0 * 2048;
  const int* tp1 = seq + b1 * 2048;
  float y0 = KQ[tp0[2047] * 64 + l];  // y_a = k_a . q
  float y1 = KQ[tp1[2047] * 64 + l];
  float r0 = 0.f, r1 = 0.f;

  // block tokens: slot j of block nb <-> t = 2047 - (64*nb + j)
  int tokA0 = (l == 0) ? 64 : tp0[2047 - l];  // slot 0 = dummy (zero row)
  int tokA1 = (l == 0) ? 64 : tp1[2047 - l];
  int tokB0 = tp0[2047 - 64 - l];
  int tokB1 = tp1[2047 - 64 - l];

  // ring-8 prefetch: sel (SGPR ring) + column (VGPR ring), static indices
  float2 c0[8], c1[8];
  int s0[8], s1[8];
#pragma unroll
  for (int k = 0; k < 8; ++k) {
    s0[k] = __builtin_amdgcn_readlane(tokA0, k);
    c0[k] = GV_s[s0[k] * 64 + l];
    s1[k] = __builtin_amdgcn_readlane(tokA1, k);
    c1[k] = GV_s[s1[k] * 64 + l];
  }

  for (int blk = 0; blk < 32; ++blk) {
    int nx0 = (blk + 2 < 32) ? tp0[2047 - 64 * (blk + 2) - l] : 64;
    int nx1 = (blk + 2 < 32) ? tp1[2047 - 64 * (blk + 2) - l] : 64;
#pragma unroll
    for (int j = 0; j < 64; ++j) {
      const int ip = j + 8;  // prefetch step index (static)
      // ---- batch 0, step j ----
      {
        const float2 gv = c0[j & 7];  // consume ring (loaded 8 steps ago)
        const int bc = s0[j & 7] & 63;
        const int sl = (ip < 64) ? __builtin_amdgcn_readlane(tokA0, ip)
                                 : __builtin_amdgcn_readlane(tokB0, ip - 64);
        s0[j & 7] = sl;
        c0[j & 7] = GV_s[sl * 64 + l];
        const float s = readlane_f(y0, bc);  // chain
        y0 = fmaf(s, gv.x, y0);
        r0 = fmaf(s, gv.y, r0);
      }
      // ---- batch 1, step j (fills batch 0's hazard slots) ----
      {
        const float2 gv = c1[j & 7];
        const int bc = s1[j & 7] & 63;
        const int sl = (ip < 64) ? __builtin_amdgcn_readlane(tokA1, ip)
                                 : __builtin_amdgcn_readlane(tokB1, ip - 64);
        s1[j & 7] = sl;
        c1[j & 7] = GV_s[sl * 64 + l];
        const float s = readlane_f(y1, bc);
        y1 = fmaf(s, gv.x, y1);
        r1 = fmaf(s, gv.y, r1);
      }
    }
    tokA0 = tokB0;
    tokB0 = nx0;
    tokA1 = tokB1;
    tokB1 = nx1;
  }

  // ---- Head: r -> Wrp -> Wout for both batches (weights staged once) ----
  float* Wb = (float*)GV_s;
  tmp[l] = r0;
  tmp[64 + l] = r1;
  __syncthreads();
  for (int i = 0; i < 64; ++i) {
    Wb[i * 65 + l] = Wrp[i * 64 + l];
    Wb[4160 + i * 65 + l] = Wout[i * 64 + l];
  }
  __syncthreads();
  float a0 = brp[l], a1 = brp[l];
#pragma unroll
  for (int j = 0; j < 64; ++j) {
    a0 = fmaf(tmp[j], Wb[l * 65 + j], a0);
    a1 = fmaf(tmp[64 + j], Wb[l * 65 + j], a1);
  }
  __syncthreads();
  tmp[l] = a0;
  tmp[64 + l] = a1;
  __syncthreads();
  float o0 = bout[l], o1 = bout[l];
#pragma unroll
  for (int i = 0; i < 64; ++i) {
    o0 = fmaf(tmp[i], Wb[4160 + l * 65 + i], o0);
    o1 = fmaf(tmp[64 + i], Wb[4160 + l * 65 + i], o1);
  }
  out[b0 * 64 + l] = o0;
  out[b1 * 64 + l] = o1;
}

extern "C" void kernel_launch(void* const* d_in, const int* in_sizes, int n_in,
                              void* d_out, int out_size, void* d_ws,
                              size_t ws_size, hipStream_t stream) {
  const int* seq = (const int*)d_in[0];
  const float* embed = (const float*)d_in[1];
  const float* W1 = (const float*)d_in[2];
  const float* b1 = (const float*)d_in[3];
  const float* W2 = (const float*)d_in[4];
  const float* b2 = (const float*)d_in[5];
  const float* gamma = (const float*)d_in[6];
  const float* beta = (const float*)d_in[7];
  const float* Wk = (const float*)d_in[8];
  const float* Wv = (const float*)d_in[9];
  const float* Wq = (const float*)d_in[10];
  const float* Wrp = (const float*)d_in[11];
  const float* brp = (const float*)d_in[12];
  const float* Wout = (const float*)d_in[13];
  const float* bout = (const float*)d_in[14];

  float* wsf = (float*)d_ws;
  float* k_tab = wsf;                   // 4096
  float* v_tab = wsf + 4096;            // 4096
  float* q_tab = wsf + 8192;            // 4096
  float2* GV = (float2*)(wsf + 12288);  // 4096 float2 = 8192 floats
  float* KQ = wsf + 20480;              // 4096

  build_tables<<<64, 64, 0, stream>>>(embed, W1, b1, W2, b2, gamma, beta, Wk,
                                      Wv, Wq, k_tab, v_tab, q_tab);
  build_gram<<<64, 64, 0, stream>>>(k_tab, q_tab, v_tab, GV, KQ);
  scan_head2<<<128, 64, 0, stream>>>(seq, GV, KQ, Wrp, brp, Wout, bout,
                                     (float*)d_out);
}

// Round 7
// 148.315 us; speedup vs baseline: 1.1040x; 1.1040x over previous
//
#include <hip/hip_runtime.h>

// ---------------------------------------------------------------------------
// DeltaModel: B=256, L=2048, H=V=64.
//  (1) hs/k/v/q depend only on token id (V=64) -> 64-entry tables.
//  (2) r = M_N q -> backward scan: for j=1..2047 (t=2047-j):
//        s_j = y[c_j];  y += s_j * (-G[:,c_j]);  r += s_j * v[c_j]
//  (3) Measured across 6 rounds: every v_readlane/readfirstlane costs ~13cy
//      of un-hideable serialization (scalar-writeback throughput), so the
//      optimization target is READLANE COUNT PER STEP, not chain latency.
//      - chain readlane(y, c_j): irreducible, 1/step.
//      - token->SGPR: tokens are 6 bits -> pack 5/word (pack_tokens kernel);
//        ONE readfirstlane per 5 steps + SALU shifts = 0.2/step.
//      Total 1.2 readlanes/step (~16cy) vs baseline's 3 (~47cy measured).
//      Column ds_read ring: 25 slots, refill distance 20, all indices static
//      (consume slot 5q+i; refill slot (5q+i-5)%25 with token S[(q+4)%5][i]
//      which is exactly token(j+20); 5 token-sets rotate, unpack at phase
//      end overwrites the just-consumed set).
//      Per-batch fma sequence identical to round-0 kernel -> bit-identical.
// ---------------------------------------------------------------------------

#define DPP_ADD_F32(x, ctrl, rm, bm, bc)                                      \
  (x) = (x) + __int_as_float(__builtin_amdgcn_update_dpp(                     \
            0, __float_as_int(x), (ctrl), (rm), (bm), (bc)))

__device__ __forceinline__ float wave_sum64(float x) {
  DPP_ADD_F32(x, 0x111, 0xf, 0xf, true);   // row_shr:1
  DPP_ADD_F32(x, 0x112, 0xf, 0xf, true);   // row_shr:2
  DPP_ADD_F32(x, 0x114, 0xf, 0xf, true);   // row_shr:4
  DPP_ADD_F32(x, 0x118, 0xf, 0xf, true);   // row_shr:8
  DPP_ADD_F32(x, 0x142, 0xa, 0xf, false);  // row_bcast:15
  DPP_ADD_F32(x, 0x143, 0xc, 0xf, false);  // row_bcast:31 -> lane 63 total
  return __int_as_float(__builtin_amdgcn_readlane(__float_as_int(x), 63));
}

__device__ __forceinline__ float readlane_f(float x, int lane) {
  return __int_as_float(__builtin_amdgcn_readlane(__float_as_int(x), lane));
}

// ---------------------------------------------------------------------------
// Kernel A: per-token tables k_n, v, q (weights staged in padded LDS).
// ---------------------------------------------------------------------------
__global__ __launch_bounds__(64) void build_tables(
    const float* __restrict__ embed, const float* __restrict__ W1,
    const float* __restrict__ b1, const float* __restrict__ W2,
    const float* __restrict__ b2, const float* __restrict__ gamma,
    const float* __restrict__ beta, const float* __restrict__ Wk,
    const float* __restrict__ Wv, const float* __restrict__ Wq,
    float* __restrict__ k_tab, float* __restrict__ v_tab,
    float* __restrict__ q_tab) {
  __shared__ float Wbuf[8448];
  __shared__ float e_s[64];
  __shared__ float f1_s[128];
  __shared__ float hs_s[64];
  const int tok = blockIdx.x;
  const int l = threadIdx.x;

  const float e = embed[tok * 64 + l];
  e_s[l] = e;
  for (int i = 0; i < 128; ++i) Wbuf[i * 65 + l] = W1[i * 64 + l];
  __syncthreads();

  float a0 = b1[l], a1 = b1[l + 64];
#pragma unroll
  for (int h = 0; h < 64; ++h) {
    a0 = fmaf(e_s[h], Wbuf[l * 65 + h], a0);
    a1 = fmaf(e_s[h], Wbuf[(l + 64) * 65 + h], a1);
  }
  f1_s[l] = fmaxf(a0, 0.f);
  f1_s[l + 64] = fmaxf(a1, 0.f);
  __syncthreads();

  for (int i = 0; i < 128; ++i)
    Wbuf[(i >> 1) * 131 + (i & 1) * 64 + l] = W2[i * 64 + l];
  __syncthreads();

  float acc = b2[l];
#pragma unroll
  for (int j = 0; j < 128; ++j) acc = fmaf(f1_s[j], Wbuf[l * 131 + j], acc);
  const float hval = e + acc;

  const float mu = wave_sum64(hval) * (1.f / 64.f);
  const float d = hval - mu;
  const float var = wave_sum64(d * d) * (1.f / 64.f);
  const float hs = d * (1.f / sqrtf(var + 1e-5f)) * gamma[l] + beta[l];
  hs_s[l] = hs;
  __syncthreads();

  for (int i = 0; i < 64; ++i) {
    Wbuf[i * 65 + l] = Wk[i * 64 + l];
    Wbuf[4224 + i * 65 + l] = Wv[i * 64 + l];
  }
  __syncthreads();
  float kk = 0.f, vv = 0.f;
#pragma unroll
  for (int h = 0; h < 64; ++h) {
    kk = fmaf(hs_s[h], Wbuf[l * 65 + h], kk);
    vv = fmaf(hs_s[h], Wbuf[4224 + l * 65 + h], vv);
  }
  __syncthreads();
  for (int i = 0; i < 64; ++i) Wbuf[i * 65 + l] = Wq[i * 64 + l];
  __syncthreads();
  float qq = 0.f;
#pragma unroll
  for (int h = 0; h < 64; ++h) qq = fmaf(hs_s[h], Wbuf[l * 65 + h], qq);

  float nrm = fmaxf(sqrtf(wave_sum64(kk * kk)), 1e-12f);
  k_tab[tok * 64 + l] = kk / nrm;
  v_tab[tok * 64 + l] = vv;
  q_tab[tok * 64 + l] = qq;
}

// ---------------------------------------------------------------------------
// Kernel B: GV[a][l] = {-G[a][l], v[a][l]} packed float2 (G NEGATED so every
// downstream update is a positive fma); KQ[a][l] = q_a.k_l.
// ---------------------------------------------------------------------------
__global__ __launch_bounds__(64) void build_gram(
    const float* __restrict__ k_tab, const float* __restrict__ q_tab,
    const float* __restrict__ v_tab, float2* __restrict__ GV,
    float* __restrict__ KQ) {
  __shared__ float k_s[4160];
  __shared__ float q_s[64];
  const int a = blockIdx.x;
  const int l = threadIdx.x;
  for (int i = 0; i < 64; ++i) k_s[i * 65 + l] = k_tab[i * 64 + l];
  q_s[l] = q_tab[a * 64 + l];
  __syncthreads();
  float g = 0.f, kq = 0.f;
#pragma unroll
  for (int h = 0; h < 64; ++h) {
    g = fmaf(k_s[a * 65 + h], k_s[l * 65 + h], g);
    kq = fmaf(q_s[h], k_s[l * 65 + h], kq);
  }
  GV[a * 64 + l] = make_float2(-g, v_tab[a * 64 + l]);
  KQ[a * 64 + l] = kq;
}

// ---------------------------------------------------------------------------
// Kernel B2: pack 5 six-bit tokens per 32-bit word, in scan order.
// word w of batch b holds tokens for steps j = 5w+1 .. 5w+5 (t = 2047-j).
// ---------------------------------------------------------------------------
__global__ __launch_bounds__(256) void pack_tokens(const int* __restrict__ seq,
                                                   int* __restrict__ pk) {
  const int idx = blockIdx.x * 256 + threadIdx.x;  // global word index
  const int b = idx / 410, w = idx - b * 410;
  const int* tp = seq + b * 2048;
  int acc = 0;
#pragma unroll
  for (int i = 0; i < 5; ++i) {
    const int j = 5 * w + 1 + i;
    const int t = (j <= 2047) ? tp[2047 - j] : 0;
    acc |= t << (6 * i);
  }
  pk[b * 412 + w] = acc;
}

// ---------------------------------------------------------------------------
// Kernel C: per-batch scan + head. One wave per batch, grid 256.
// ---------------------------------------------------------------------------
__global__ __launch_bounds__(64, 1) void scan_head(
    const int* __restrict__ seq, const float2* __restrict__ GVg,
    const float* __restrict__ KQ, const int* __restrict__ pk,
    const float* __restrict__ Wrp, const float* __restrict__ brp,
    const float* __restrict__ Wout, const float* __restrict__ bout,
    float* __restrict__ out) {
  __shared__ float2 GV_s[4160];  // cols; later reused as head weight buffer
  __shared__ int pk_s[448];      // packed tokens (410 used, rest zero)
  __shared__ float tmp[64];
  const int b = blockIdx.x;
  const int l = threadIdx.x;

#pragma unroll
  for (int i = 0; i < 32; ++i)
    ((float4*)GV_s)[l + 64 * i] = ((const float4*)GVg)[l + 64 * i];
  const int* pkb = pk + b * 412;
#pragma unroll
  for (int i = 0; i < 7; ++i) {
    const int idx = l + 64 * i;
    pk_s[idx] = (idx < 410) ? pkb[idx] : 0;
  }
  __syncthreads();

  const int* tokp = seq + b * 2048;
  const int qt = tokp[2047];  // t=2047 token -> q
  float y = KQ[qt * 64 + l];  // y_a = k_a . q
  float r = 0.f;

  // ---- token sets: S[k] holds subgroup (5 tokens); vw = packed-word ring --
  int S[5][5];
  int vw[5];
#pragma unroll
  for (int k = 0; k < 5; ++k) {
    const int u = __builtin_amdgcn_readfirstlane(pk_s[k]);
#pragma unroll
    for (int i = 0; i < 5; ++i) S[k][i] = (u >> (6 * i)) & 63;
  }
  vw[0] = pk_s[5];
  vw[1] = pk_s[6];
  vw[2] = 0;
  vw[3] = 0;
  vw[4] = 0;

  // ---- column ring: 25 slots; prime slots 0..19 with cols for j=1..20 ----
  float2 c[25];
#pragma unroll
  for (int s = 0; s < 20; ++s) c[s] = GV_s[S[s / 5][s % 5] * 64 + l];

  // ---- main loop: 81 iters x 5 phases x 5 steps = j=1..2025 --------------
  for (int m = 0; m < 81; ++m) {
    const int wb = 5 * m;
#pragma unroll
    for (int q = 0; q < 5; ++q) {
      vw[(q + 2) % 5] = pk_s[wb + q + 7];  // packed word for later unpack
#pragma unroll
      for (int i = 0; i < 5; ++i) {
        const float2 gv = c[5 * q + i];  // col for step j (prefetched)
        // refill slot (5q+i-5)%25 with col for step j+20
        c[(q == 0) ? (20 + i) : (5 * q - 5 + i)] =
            GV_s[S[(q + 4) % 5][i] * 64 + l];
        const float sv = readlane_f(y, S[q][i]);  // chain: the ONE readlane
        y = fmaf(sv, gv.x, y);
        r = fmaf(sv, gv.y, r);
      }
      // unpack next subgroup (5m+q+5) into the just-consumed set
      const int u = __builtin_amdgcn_readfirstlane(vw[q]);
#pragma unroll
      for (int i = 0; i < 5; ++i) S[q][i] = (u >> (6 * i)) & 63;
    }
  }

  // ---- tail: subgroups 405..408 (j=2026..2045), no unpack ---------------
#pragma unroll
  for (int q = 0; q < 4; ++q) {
#pragma unroll
    for (int i = 0; i < 5; ++i) {
      const float2 gv = c[5 * q + i];
      c[(q == 0) ? (20 + i) : (5 * q - 5 + i)] =
          GV_s[S[(q + 4) % 5][i] * 64 + l];
      const float sv = readlane_f(y, S[q][i]);
      y = fmaf(sv, gv.x, y);
      r = fmaf(sv, gv.y, r);
    }
  }
  // ---- final steps j=2046, 2047 (slots 20, 21; tokens S[4][0..1]) -------
  {
    const float2 gv = c[20];
    const float sv = readlane_f(y, S[4][0]);
    y = fmaf(sv, gv.x, y);
    r = fmaf(sv, gv.y, r);
  }
  {
    const float2 gv = c[21];
    const float sv = readlane_f(y, S[4][1]);
    r = fmaf(sv, gv.y, r);
  }

  // ---- Head: r -> Wrp -> Wout (weights staged padded into GV_s memory) --
  float* Wb = (float*)GV_s;
  tmp[l] = r;
  __syncthreads();
  for (int i = 0; i < 64; ++i) {
    Wb[i * 65 + l] = Wrp[i * 64 + l];
    Wb[4160 + i * 65 + l] = Wout[i * 64 + l];
  }
  __syncthreads();
  float acc = brp[l];
#pragma unroll
  for (int j = 0; j < 64; ++j) acc = fmaf(tmp[j], Wb[l * 65 + j], acc);
  __syncthreads();
  tmp[l] = acc;
  __syncthreads();
  float o = bout[l];
#pragma unroll
  for (int i = 0; i < 64; ++i) o = fmaf(tmp[i], Wb[4160 + l * 65 + i], o);
  out[b * 64 + l] = o;
}

extern "C" void kernel_launch(void* const* d_in, const int* in_sizes, int n_in,
                              void* d_out, int out_size, void* d_ws,
                              size_t ws_size, hipStream_t stream) {
  const int* seq = (const int*)d_in[0];
  const float* embed = (const float*)d_in[1];
  const float* W1 = (const float*)d_in[2];
  const float* b1 = (const float*)d_in[3];
  const float* W2 = (const float*)d_in[4];
  const float* b2 = (const float*)d_in[5];
  const float* gamma = (const float*)d_in[6];
  const float* beta = (const float*)d_in[7];
  const float* Wk = (const float*)d_in[8];
  const float* Wv = (const float*)d_in[9];
  const float* Wq = (const float*)d_in[10];
  const float* Wrp = (const float*)d_in[11];
  const float* brp = (const float*)d_in[12];
  const float* Wout = (const float*)d_in[13];
  const float* bout = (const float*)d_in[14];

  float* wsf = (float*)d_ws;
  float* k_tab = wsf;                   // 4096
  float* v_tab = wsf + 4096;            // 4096
  float* q_tab = wsf + 8192;            // 4096
  float2* GV = (float2*)(wsf + 12288);  // 4096 float2 = 8192 floats
  float* KQ = wsf + 20480;              // 4096
  int* pk = (int*)(wsf + 24576);        // 256 * 412 ints

  build_tables<<<64, 64, 0, stream>>>(embed, W1, b1, W2, b2, gamma, beta, Wk,
                                      Wv, Wq, k_tab, v_tab, q_tab);
  build_gram<<<64, 64, 0, stream>>>(k_tab, q_tab, v_tab, GV, KQ);
  pack_tokens<<<410, 256, 0, stream>>>(seq, pk);
  scan_head<<<256, 64, 0, stream>>>(seq, GV, KQ, pk, Wrp, brp, Wout, bout,
                                    (float*)d_out);
}